// Round 14
// baseline (237.375 us; speedup 1.0000x reference)
//
#include <hip/hip_runtime.h>
#include <hip/hip_bf16.h>
#include <math.h>

#define NEG_SLOPE 0.2f
#define CHUNK2 2048
#define PGROUPS 32

typedef __attribute__((ext_vector_type(8))) short bf16x8;
typedef __attribute__((ext_vector_type(4))) float f32x4;
typedef __attribute__((ext_vector_type(2))) float f32x2_t;

__device__ __forceinline__ float lrelu(float a) { return a >= 0.f ? a : NEG_SLOPE * a; }
__device__ __forceinline__ unsigned short f2bu(float v) {
  unsigned u = __float_as_uint(v);
  u += 0x7fffu + ((u >> 16) & 1u);  // RNE
  return (unsigned short)(u >> 16);
}
// fp8 e4m3 (OCP on gfx950) HW conversions
__device__ __forceinline__ unsigned char f2fp8(float v) {
  return (unsigned char)(__builtin_amdgcn_cvt_pk_fp8_f32(v, v, 0, false) & 0xFF);
}
__device__ __forceinline__ void fp8x4_dec(unsigned v, float& a, float& b, float& c, float& d) {
  f32x2_t lo = __builtin_amdgcn_cvt_pk_f32_fp8(v, false);
  f32x2_t hi = __builtin_amdgcn_cvt_pk_f32_fp8(v, true);
  a = lo.x; b = lo.y; c = hi.x; d = hi.y;
}

// ================= fused prep: bf16 casts (blocks < castBlocks) || bucket hist =================
__global__ __launch_bounds__(256) void prep_kernel(
    const float4* __restrict__ a0, ushort4* __restrict__ d0, int n0,
    const float4* __restrict__ a1, ushort4* __restrict__ d1, int n1,
    const float4* __restrict__ a2, ushort4* __restrict__ d2, int n2,
    const int* __restrict__ ei, int* __restrict__ bhist, int E0, int Etot, int NBUCK,
    int castBlocks, int histBlocks) {
  __shared__ int hsm[256];
  if (blockIdx.x < (unsigned)castBlocks) {
    int total = n0 + n1 + n2;
    for (int i = blockIdx.x * 256 + threadIdx.x; i < total; i += castBlocks * 256) {
      const float4* s;
      ushort4* d;
      int j = i;
      if (j < n0) { s = a0; d = d0; }
      else if (j < n0 + n1) { j -= n0; s = a1; d = d1; }
      else { j -= n0 + n1; s = a2; d = d2; }
      float4 v = s[j];
      d[j] = make_ushort4(f2bu(v.x), f2bu(v.y), f2bu(v.z), f2bu(v.w));
    }
  } else {
    int bid = blockIdx.x - castBlocks;
    int t = threadIdx.x;
    hsm[t] = 0;
    __syncthreads();
    for (int e = bid * 256 + t; e < Etot; e += histBlocks * 256) {
      int dst = (e < E0) ? ei[E0 + e] : (e - E0);
      atomicAdd(&hsm[dst >> 8], 1);
    }
    __syncthreads();
    if (t < NBUCK && hsm[t]) atomicAdd(&bhist[t], hsm[t]);
  }
}

// ================= bucket scan =================
__global__ __launch_bounds__(256) void bucket_scan_kernel(const int* __restrict__ bhist,
    int* __restrict__ bucketOff, int* __restrict__ cursor, int* __restrict__ rowptrN,
    int NBUCK, int Etot) {
  __shared__ int s[256];
  int t = threadIdx.x;
  int v = (t < NBUCK) ? bhist[t] : 0;
  s[t] = v;
  __syncthreads();
  for (int off = 1; off < 256; off <<= 1) {
    int u = (t >= off) ? s[t - off] : 0;
    __syncthreads();
    s[t] += u;
    __syncthreads();
  }
  int excl = s[t] - v;
  if (t < NBUCK) { bucketOff[t] = excl; cursor[t] = excl; }
  if (t == 0) { bucketOff[NBUCK] = Etot; *rowptrN = Etot; }
}

// ================= GEMM tile (bf16 MFMA, fp8 out) + alpha epilogue =================
__device__ void gemm_tile(const unsigned short* __restrict__ A,
    const unsigned short* __restrict__ B, unsigned char* __restrict__ C8,
    const float* __restrict__ att_s, const float* __restrict__ att_d,
    float* __restrict__ as_, float* __restrict__ ad_,
    int M, int K, int Ncol, int H, int bx, int by, char* smem) {
  unsigned short (*Al)[40] = (unsigned short (*)[40])smem;           // 5120 B
  unsigned short (*Bt)[40] = (unsigned short (*)[40])(smem + 5120);  // 5120 B
  float* sal = (float*)(smem + 10240);  // [2][64]
  float* sad = (float*)(smem + 10752);  // [2][64]
  const int tid = threadIdx.x;
  const int row0 = by * 64, col0 = bx * 64;
  const int lane = tid & 63, wave = tid >> 6;
  const int wm = wave >> 1, wn = wave & 1;
  const int l15 = lane & 15, q = lane >> 4;

  f32x4 acc[2][2] = {};

  const int am = tid >> 2, ac = (tid & 3) * 8;
  const int bk = tid >> 3, bn = (tid & 7) * 8;

  for (int k0 = 0; k0 < K; k0 += 32) {
    ushort4 av0 = make_ushort4(0, 0, 0, 0), av1 = av0;
    if (row0 + am < M) {
      const ushort4* ap = (const ushort4*)(A + (size_t)(row0 + am) * K + k0 + ac);
      av0 = ap[0]; av1 = ap[1];
    }
    *(ushort4*)&Al[am][ac] = av0;
    *(ushort4*)&Al[am][ac + 4] = av1;
    {
      const ushort4* bp = (const ushort4*)(B + (size_t)(k0 + bk) * Ncol + col0 + bn);
      ushort4 b0 = bp[0], b1 = bp[1];
      Bt[bn + 0][bk] = b0.x; Bt[bn + 1][bk] = b0.y;
      Bt[bn + 2][bk] = b0.z; Bt[bn + 3][bk] = b0.w;
      Bt[bn + 4][bk] = b1.x; Bt[bn + 5][bk] = b1.y;
      Bt[bn + 6][bk] = b1.z; Bt[bn + 7][bk] = b1.w;
    }
    __syncthreads();
    bf16x8 af[2], bf[2];
#pragma unroll
    for (int mi = 0; mi < 2; mi++)
      af[mi] = *(const bf16x8*)&Al[wm * 32 + mi * 16 + l15][q * 8];
#pragma unroll
    for (int ni = 0; ni < 2; ni++)
      bf[ni] = *(const bf16x8*)&Bt[wn * 32 + ni * 16 + l15][q * 8];
#pragma unroll
    for (int mi = 0; mi < 2; mi++)
#pragma unroll
      for (int ni = 0; ni < 2; ni++)
        acc[mi][ni] = __builtin_amdgcn_mfma_f32_16x16x32_bf16(af[mi], bf[ni], acc[mi][ni], 0, 0, 0);
    __syncthreads();
  }
  // fp8 store
#pragma unroll
  for (int mi = 0; mi < 2; mi++) {
#pragma unroll
    for (int r = 0; r < 4; r++) {
      int grow = row0 + wm * 32 + mi * 16 + q * 4 + r;
      if (grow < M) {
#pragma unroll
        for (int ni = 0; ni < 2; ni++) {
          int gcol = col0 + wn * 32 + ni * 16 + l15;
          C8[(size_t)grow * Ncol + gcol] = f2fp8(acc[mi][ni][r]);
        }
      }
    }
  }
  // alpha epilogue: per-row dot with att vectors over this block's 64 cols
  float atts0 = att_s[col0 + wn * 32 + l15];
  float atts1 = att_s[col0 + wn * 32 + 16 + l15];
  float attd0 = att_d[col0 + wn * 32 + l15];
  float attd1 = att_d[col0 + wn * 32 + 16 + l15];
#pragma unroll
  for (int mi = 0; mi < 2; mi++) {
#pragma unroll
    for (int r = 0; r < 4; r++) {
      float vs = acc[mi][0][r] * atts0 + acc[mi][1][r] * atts1;
      float vd = acc[mi][0][r] * attd0 + acc[mi][1][r] * attd1;
#pragma unroll
      for (int off = 1; off < 16; off <<= 1) {
        vs += __shfl_xor(vs, off);
        vd += __shfl_xor(vd, off);
      }
      if (l15 == 0) {
        int rl = wm * 32 + mi * 16 + q * 4 + r;
        sal[wn * 64 + rl] = vs;
        sad[wn * 64 + rl] = vd;
      }
    }
  }
  __syncthreads();
  if (tid < 64) {
    int grow = row0 + tid;
    if (grow < M) {
      as_[(size_t)grow * H + bx] = sal[tid] + sal[64 + tid];
      ad_[(size_t)grow * H + bx] = sad[tid] + sad[64 + tid];
    }
  }
}

__global__ __launch_bounds__(256) void gemm_alpha_kernel(const unsigned short* __restrict__ A,
    const unsigned short* __restrict__ B, unsigned char* __restrict__ C8,
    const float* __restrict__ att_s, const float* __restrict__ att_d,
    float* __restrict__ as_, float* __restrict__ ad_, int M, int K, int Ncol, int H) {
  __shared__ __align__(16) char smem[11264];
  gemm_tile(A, B, C8, att_s, att_d, as_, ad_, M, K, Ncol, H, blockIdx.x, blockIdx.y, smem);
}

// ================= fused: bucket scatter (blocks < NSC) || gemm1 =================
__global__ __launch_bounds__(256) void gemm1_scatter_kernel(
    const unsigned short* __restrict__ A, const unsigned short* __restrict__ B,
    unsigned char* __restrict__ C8, const float* __restrict__ att_s,
    const float* __restrict__ att_d, float* __restrict__ as_, float* __restrict__ ad_,
    int M, int K, int Ncol, int H, int GX,
    const int* __restrict__ ei, int* __restrict__ cursor, int* __restrict__ pairs,
    int E0, int Etot, int NBUCK, int NSC) {
  __shared__ __align__(16) char smem[18432];
  if (blockIdx.x < (unsigned)NSC) {
    int2* stage = (int2*)smem;            // 16384 B
    int* h = (int*)(smem + 16384);        // 1024 B
    int* base = (int*)(smem + 17408);     // 1024 B
    int t = threadIdx.x;
    int e0 = blockIdx.x * CHUNK2;
    h[t] = 0;
    __syncthreads();
    int cnt = Etot - e0;
    if (cnt > CHUNK2) cnt = CHUNK2;
    for (int i = t; i < cnt; i += 256) {
      int e = e0 + i;
      int s, d;
      if (e < E0) { s = ei[e]; d = ei[E0 + e]; } else { s = d = e - E0; }
      stage[i] = make_int2((s << 8) | (d & 255), d >> 8);
      atomicAdd(&h[d >> 8], 1);
    }
    __syncthreads();
    if (t < NBUCK && h[t]) base[t] = atomicAdd(&cursor[t], h[t]);
    __syncthreads();
    for (int i = t; i < cnt; i += 256) {
      int2 p = stage[i];
      int pos = atomicAdd(&base[p.y], 1);
      pairs[pos] = p.x;
    }
  } else {
    int flat = blockIdx.x - NSC;
    gemm_tile(A, B, C8, att_s, att_d, as_, ad_, M, K, Ncol, H, flat % GX, flat / GX, smem);
  }
}

// ================= per-bucket fine CSR =================
__global__ __launch_bounds__(256) void csr_build_kernel(const int* __restrict__ pairs,
    const int* __restrict__ bucketOff, int* __restrict__ rowptr, int* __restrict__ csr_src,
    int N) {
  int b = blockIdx.x, t = threadIdx.x;
  int base = bucketOff[b], cnt = bucketOff[b + 1] - base;
  int n0 = b << 8;
  __shared__ int h[256];
  __shared__ int s[256];
  __shared__ int ex[256];
  h[t] = 0;
  __syncthreads();
  for (int i = t; i < cnt; i += 256) atomicAdd(&h[pairs[base + i] & 255], 1);
  __syncthreads();
  int v = h[t];
  s[t] = v;
  __syncthreads();
  for (int off = 1; off < 256; off <<= 1) {
    int u = (t >= off) ? s[t - off] : 0;
    __syncthreads();
    s[t] += u;
    __syncthreads();
  }
  ex[t] = s[t] - v;
  if (n0 + t < N) rowptr[n0 + t] = base + ex[t];
  __syncthreads();
  for (int i = t; i < cnt; i += 256) {
    int p = pairs[base + i];
    int pos = atomicAdd(&ex[p & 255], 1);
    csr_src[base + pos] = ((unsigned)p) >> 8;
  }
}

// ================= layer-1 aggregate: quarter-wave per node, 16 ch/lane =================
// lane l15 owns channels l15*16..l15*16+15 (uint4 fp8 gather); 4 node streams/wave,
// 16 nodes/block. exp computed once per lane per edge (head = l15>>2); each lane
// accumulates its own wsum -> no cross-lane reduction.
__global__ __launch_bounds__(256) void aggr1_kernel(const int* __restrict__ rowptr,
    const int* __restrict__ csr_src, const float* __restrict__ as_,
    const float* __restrict__ ad_, const uint4* __restrict__ h1f8,  // [N][16] uint4
    const float* __restrict__ b1, unsigned short* __restrict__ out1, int Nn) {
  int lane = threadIdx.x & 63, wv = threadIdx.x >> 6;
  int q = lane >> 4, l15 = lane & 15;
  int n = (blockIdx.x * 4 + wv) * 4 + q;
  if (n >= Nn) return;
  int row = rowptr[n], deg = rowptr[n + 1] - row;
  int hh = l15 >> 2;
  float adv = ad_[n * 4 + hh];
  const uint4* hb = h1f8 + l15;
  float acc[16] = {};
  float wsum = 0.f;
  int s = 0;
  for (; s + 2 <= deg; s += 2) {
    int i0 = csr_src[row + s], i1 = csr_src[row + s + 1];
    float a0v = as_[i0 * 4 + hh], a1v = as_[i1 * 4 + hh];
    uint4 x0 = hb[(size_t)i0 * 16];
    uint4 x1 = hb[(size_t)i1 * 16];
    float w0 = __expf(lrelu(a0v + adv));
    float w1 = __expf(lrelu(a1v + adv));
    wsum += w0 + w1;
    float c0, c1, c2, c3;
    fp8x4_dec(x0.x, c0, c1, c2, c3);
    acc[0] = fmaf(w0, c0, acc[0]); acc[1] = fmaf(w0, c1, acc[1]);
    acc[2] = fmaf(w0, c2, acc[2]); acc[3] = fmaf(w0, c3, acc[3]);
    fp8x4_dec(x0.y, c0, c1, c2, c3);
    acc[4] = fmaf(w0, c0, acc[4]); acc[5] = fmaf(w0, c1, acc[5]);
    acc[6] = fmaf(w0, c2, acc[6]); acc[7] = fmaf(w0, c3, acc[7]);
    fp8x4_dec(x0.z, c0, c1, c2, c3);
    acc[8] = fmaf(w0, c0, acc[8]); acc[9] = fmaf(w0, c1, acc[9]);
    acc[10] = fmaf(w0, c2, acc[10]); acc[11] = fmaf(w0, c3, acc[11]);
    fp8x4_dec(x0.w, c0, c1, c2, c3);
    acc[12] = fmaf(w0, c0, acc[12]); acc[13] = fmaf(w0, c1, acc[13]);
    acc[14] = fmaf(w0, c2, acc[14]); acc[15] = fmaf(w0, c3, acc[15]);
    fp8x4_dec(x1.x, c0, c1, c2, c3);
    acc[0] = fmaf(w1, c0, acc[0]); acc[1] = fmaf(w1, c1, acc[1]);
    acc[2] = fmaf(w1, c2, acc[2]); acc[3] = fmaf(w1, c3, acc[3]);
    fp8x4_dec(x1.y, c0, c1, c2, c3);
    acc[4] = fmaf(w1, c0, acc[4]); acc[5] = fmaf(w1, c1, acc[5]);
    acc[6] = fmaf(w1, c2, acc[6]); acc[7] = fmaf(w1, c3, acc[7]);
    fp8x4_dec(x1.z, c0, c1, c2, c3);
    acc[8] = fmaf(w1, c0, acc[8]); acc[9] = fmaf(w1, c1, acc[9]);
    acc[10] = fmaf(w1, c2, acc[10]); acc[11] = fmaf(w1, c3, acc[11]);
    fp8x4_dec(x1.w, c0, c1, c2, c3);
    acc[12] = fmaf(w1, c0, acc[12]); acc[13] = fmaf(w1, c1, acc[13]);
    acc[14] = fmaf(w1, c2, acc[14]); acc[15] = fmaf(w1, c3, acc[15]);
  }
  if (s < deg) {
    int i0 = csr_src[row + s];
    float w0 = __expf(lrelu(as_[i0 * 4 + hh] + adv));
    wsum += w0;
    uint4 x0 = hb[(size_t)i0 * 16];
    float c0, c1, c2, c3;
    fp8x4_dec(x0.x, c0, c1, c2, c3);
    acc[0] = fmaf(w0, c0, acc[0]); acc[1] = fmaf(w0, c1, acc[1]);
    acc[2] = fmaf(w0, c2, acc[2]); acc[3] = fmaf(w0, c3, acc[3]);
    fp8x4_dec(x0.y, c0, c1, c2, c3);
    acc[4] = fmaf(w0, c0, acc[4]); acc[5] = fmaf(w0, c1, acc[5]);
    acc[6] = fmaf(w0, c2, acc[6]); acc[7] = fmaf(w0, c3, acc[7]);
    fp8x4_dec(x0.z, c0, c1, c2, c3);
    acc[8] = fmaf(w0, c0, acc[8]); acc[9] = fmaf(w0, c1, acc[9]);
    acc[10] = fmaf(w0, c2, acc[10]); acc[11] = fmaf(w0, c3, acc[11]);
    fp8x4_dec(x0.w, c0, c1, c2, c3);
    acc[12] = fmaf(w0, c0, acc[12]); acc[13] = fmaf(w0, c1, acc[13]);
    acc[14] = fmaf(w0, c2, acc[14]); acc[15] = fmaf(w0, c3, acc[15]);
  }
  float vinv = 1.f / wsum;
  int c0i = l15 * 16;
  unsigned short ob[16];
#pragma unroll
  for (int k = 0; k < 4; k++) {
    float4 bb = *(const float4*)(b1 + c0i + k * 4);
    float r0 = fmaf(acc[k * 4 + 0], vinv, bb.x);
    float r1 = fmaf(acc[k * 4 + 1], vinv, bb.y);
    float r2 = fmaf(acc[k * 4 + 2], vinv, bb.z);
    float r3 = fmaf(acc[k * 4 + 3], vinv, bb.w);
    ob[k * 4 + 0] = f2bu(r0 > 0.f ? r0 : 0.f);
    ob[k * 4 + 1] = f2bu(r1 > 0.f ? r1 : 0.f);
    ob[k * 4 + 2] = f2bu(r2 > 0.f ? r2 : 0.f);
    ob[k * 4 + 3] = f2bu(r3 > 0.f ? r3 : 0.f);
  }
  *(ushort4*)(out1 + (size_t)n * 256 + c0i) = *(ushort4*)&ob[0];
  *(ushort4*)(out1 + (size_t)n * 256 + c0i + 4) = *(ushort4*)&ob[4];
  *(ushort4*)(out1 + (size_t)n * 256 + c0i + 8) = *(ushort4*)&ob[8];
  *(ushort4*)(out1 + (size_t)n * 256 + c0i + 12) = *(ushort4*)&ob[12];
}

// ================= layer-2 aggregate + relu + pool (grouped atomics, unroll 8) =================
__global__ __launch_bounds__(256) void aggr2_pool_kernel(const int* __restrict__ rowptr,
    const int* __restrict__ csr_src, const float* __restrict__ as_,
    const float* __restrict__ ad_, const unsigned* __restrict__ h2f8,
    const float* __restrict__ b2, float* __restrict__ pooled_grp, int Nn) {
  int lane = threadIdx.x & 63, wv = threadIdx.x >> 6;
  int q = lane >> 4, l15 = lane & 15;
  int c0 = l15 * 4;
  const unsigned* hb = h2f8 + l15;
  float p0 = 0.f, p1 = 0.f, p2 = 0.f, p3 = 0.f;
  int stream = (blockIdx.x * 4 + wv) * 4 + q;
  int nstreams = gridDim.x * 16;
  for (int n = stream; n < Nn; n += nstreams) {
    int row = rowptr[n], deg = rowptr[n + 1] - row;
    float adv = ad_[n];
    float a0 = 0.f, a1 = 0.f, a2 = 0.f, a3 = 0.f, wsum = 0.f;
    int s = 0;
    for (; s + 8 <= deg; s += 8) {
      int idx[8];
      float al[8];
      unsigned xv[8];
#pragma unroll
      for (int j = 0; j < 8; j++) idx[j] = csr_src[row + s + j];
#pragma unroll
      for (int j = 0; j < 8; j++) al[j] = as_[idx[j]];
#pragma unroll
      for (int j = 0; j < 8; j++) xv[j] = hb[(size_t)idx[j] * 16];
#pragma unroll
      for (int j = 0; j < 8; j++) {
        float w = __expf(lrelu(al[j] + adv));
        wsum += w;
        float c0f, c1f, c2f, c3f;
        fp8x4_dec(xv[j], c0f, c1f, c2f, c3f);
        a0 = fmaf(w, c0f, a0); a1 = fmaf(w, c1f, a1);
        a2 = fmaf(w, c2f, a2); a3 = fmaf(w, c3f, a3);
      }
    }
    if (s + 4 <= deg) {
      int idx[4];
      float al[4];
      unsigned xv[4];
#pragma unroll
      for (int j = 0; j < 4; j++) idx[j] = csr_src[row + s + j];
#pragma unroll
      for (int j = 0; j < 4; j++) al[j] = as_[idx[j]];
#pragma unroll
      for (int j = 0; j < 4; j++) xv[j] = hb[(size_t)idx[j] * 16];
#pragma unroll
      for (int j = 0; j < 4; j++) {
        float w = __expf(lrelu(al[j] + adv));
        wsum += w;
        float c0f, c1f, c2f, c3f;
        fp8x4_dec(xv[j], c0f, c1f, c2f, c3f);
        a0 = fmaf(w, c0f, a0); a1 = fmaf(w, c1f, a1);
        a2 = fmaf(w, c2f, a2); a3 = fmaf(w, c3f, a3);
      }
      s += 4;
    }
    for (; s < deg; s++) {
      int i0 = csr_src[row + s];
      float w = __expf(lrelu(as_[i0] + adv));
      wsum += w;
      float c0f, c1f, c2f, c3f;
      fp8x4_dec(hb[(size_t)i0 * 16], c0f, c1f, c2f, c3f);
      a0 = fmaf(w, c0f, a0); a1 = fmaf(w, c1f, a1);
      a2 = fmaf(w, c2f, a2); a3 = fmaf(w, c3f, a3);
    }
    float vinv = 1.f / wsum;
    float4 bb = *(const float4*)(b2 + c0);
    float r0 = fmaf(a0, vinv, bb.x), r1 = fmaf(a1, vinv, bb.y);
    float r2 = fmaf(a2, vinv, bb.z), r3 = fmaf(a3, vinv, bb.w);
    p0 += r0 > 0.f ? r0 : 0.f; p1 += r1 > 0.f ? r1 : 0.f;
    p2 += r2 > 0.f ? r2 : 0.f; p3 += r3 > 0.f ? r3 : 0.f;
  }
  __shared__ float4 sred[4][4][16];
  sred[wv][q][l15] = make_float4(p0, p1, p2, p3);
  __syncthreads();
  if (threadIdx.x < 64) {
    int slot = threadIdx.x >> 2, comp = threadIdx.x & 3;
    float acc = 0.f;
#pragma unroll
    for (int i = 0; i < 4; i++)
#pragma unroll
      for (int j = 0; j < 4; j++) {
        float4 v = sred[i][j][slot];
        acc += comp == 0 ? v.x : (comp == 1 ? v.y : (comp == 2 ? v.z : v.w));
      }
    atomicAdd(&pooled_grp[(blockIdx.x & (PGROUPS - 1)) * 64 + slot * 4 + comp], acc);
  }
}

// ================= pooled_grp[32][64] -> fc + log_softmax (one block) =================
__global__ __launch_bounds__(64) void pool_head_kernel(const float* __restrict__ pooled_grp,
    const float* __restrict__ fc_w, const float* __restrict__ fc_b,
    float* __restrict__ out, float invN) {
  int t = threadIdx.x;
  __shared__ float pl[64];
  __shared__ float lg[40];
  __shared__ float lse;
  float acc = 0.f;
#pragma unroll
  for (int g = 0; g < PGROUPS; g++) acc += pooled_grp[g * 64 + t];
  pl[t] = acc * invN;
  __syncthreads();
  if (t < 40) {
    float sm = fc_b[t];
    for (int c = 0; c < 64; c++) sm = fmaf(pl[c], fc_w[c * 40 + t], sm);
    lg[t] = sm;
  }
  __syncthreads();
  if (t == 0) {
    float m = -1e30f;
    for (int j = 0; j < 40; j++) m = fmaxf(m, lg[j]);
    float su = 0.f;
    for (int j = 0; j < 40; j++) su += expf(lg[j] - m);
    lse = m + logf(su);
  }
  __syncthreads();
  if (t < 40) out[t] = lg[t] - lse;
}

extern "C" void kernel_launch(void* const* d_in, const int* in_sizes, int n_in,
                              void* d_out, int out_size, void* d_ws, size_t ws_size,
                              hipStream_t stream) {
  const float* x        = (const float*)d_in[0];
  const int*   ei       = (const int*)d_in[1];
  const float* W1       = (const float*)d_in[2];
  const float* att_src1 = (const float*)d_in[3];
  const float* att_dst1 = (const float*)d_in[4];
  const float* b1       = (const float*)d_in[5];
  const float* W2       = (const float*)d_in[6];
  const float* att_src2 = (const float*)d_in[7];
  const float* att_dst2 = (const float*)d_in[8];
  const float* b2       = (const float*)d_in[9];
  const float* fc_w     = (const float*)d_in[10];
  const float* fc_b     = (const float*)d_in[11];
  float* out = (float*)d_out;

  const int N    = in_sizes[0] / 128;  // 50000
  const int E0   = in_sizes[1] / 2;    // 800000
  const int Etot = E0 + N;
  const int NBUCK = (N + 255) >> 8;               // 196
  const int NSC  = (Etot + CHUNK2 - 1) / CHUNK2;  // 416
  const int GBY  = (N + 63) / 64;                 // 782
  const int AGG2_BLOCKS = 2048;

  char* wsb = (char*)d_ws;
  size_t o = 0;
  auto alloc = [&](size_t bytes) { char* p = wsb + o; o += (bytes + 15) & ~(size_t)15; return p; };
  unsigned short* xb   = (unsigned short*)alloc((size_t)N * 128 * 2);
  unsigned short* w1b  = (unsigned short*)alloc(128 * 256 * 2);
  unsigned short* w2b  = (unsigned short*)alloc(256 * 64 * 2);
  unsigned char*  h1f8 = (unsigned char*)alloc((size_t)N * 256);       // fp8; reused as h2 fp8
  unsigned short* out1 = (unsigned short*)alloc((size_t)N * 256 * 2);  // bf16
  float* as1  = (float*)alloc((size_t)N * 4 * 4);
  float* ad1  = (float*)alloc((size_t)N * 4 * 4);
  float* as2  = (float*)alloc((size_t)N * 4);
  float* ad2  = (float*)alloc((size_t)N * 4);
  int* rowptr = (int*)alloc((size_t)(N + 1) * 4);
  int* bhist  = (int*)alloc(256 * 4);
  int* bucketOff = (int*)alloc(257 * 4);
  int* cursor = (int*)alloc(256 * 4);
  int* pairs  = (int*)alloc((size_t)Etot * 4);
  int* csr_src = (int*)alloc((size_t)Etot * 4);
  float* pooled_grp = (float*)alloc((size_t)PGROUPS * 64 * 4);

  dim3 blk(256);

  // ---- prep: casts || bucket hist; zero bhist + pooled groups ----
  hipMemsetAsync(bhist, 0, 256 * sizeof(int), stream);
  hipMemsetAsync(pooled_grp, 0, (size_t)PGROUPS * 64 * sizeof(float), stream);
  prep_kernel<<<512 + 256, blk, 0, stream>>>(
      (const float4*)x, (ushort4*)xb, N * 128 / 4,
      (const float4*)W1, (ushort4*)w1b, 128 * 256 / 4,
      (const float4*)W2, (ushort4*)w2b, 256 * 64 / 4,
      ei, bhist, E0, Etot, NBUCK, 512, 256);
  bucket_scan_kernel<<<1, blk, 0, stream>>>(bhist, bucketOff, cursor, rowptr + N, NBUCK, Etot);

  // ---- gemm1 (+alpha1 epilogue) || bucket scatter ----
  gemm1_scatter_kernel<<<NSC + 4 * GBY, blk, 0, stream>>>(
      xb, w1b, h1f8, att_src1, att_dst1, as1, ad1, N, 128, 256, 4, 4,
      ei, cursor, pairs, E0, Etot, NBUCK, NSC);
  csr_build_kernel<<<NBUCK, blk, 0, stream>>>(pairs, bucketOff, rowptr, csr_src, N);

  // ---- layer-1 aggregate (quarter-wave, 16 nodes/block) ----
  aggr1_kernel<<<(N + 15) / 16, blk, 0, stream>>>(rowptr, csr_src, as1, ad1,
                                                  (const uint4*)h1f8, b1, out1, N);

  // ---- layer 2: gemm2 (+alpha2 epilogue), aggregate + grouped pool atomics ----
  gemm_alpha_kernel<<<dim3(1, GBY), blk, 0, stream>>>(out1, w2b, h1f8, att_src2, att_dst2,
                                                      as2, ad2, N, 256, 64, 1);
  aggr2_pool_kernel<<<AGG2_BLOCKS, blk, 0, stream>>>(rowptr, csr_src, as2, ad2,
                                                     (const unsigned*)h1f8, b2, pooled_grp, N);

  // ---- epilogue ----
  pool_head_kernel<<<1, 64, 0, stream>>>(pooled_grp, fc_w, fc_b, out, 1.0f / (float)N);
}

// Round 15
// 223.462 us; speedup vs baseline: 1.0623x; 1.0623x over previous
//
#include <hip/hip_runtime.h>
#include <hip/hip_bf16.h>
#include <math.h>

#define NEG_SLOPE 0.2f
#define CHUNK2 2048
#define PGROUPS 32

typedef __attribute__((ext_vector_type(8))) short bf16x8;
typedef __attribute__((ext_vector_type(4))) float f32x4;
typedef __attribute__((ext_vector_type(2))) float f32x2_t;

__device__ __forceinline__ float lrelu(float a) { return a >= 0.f ? a : NEG_SLOPE * a; }
__device__ __forceinline__ unsigned short f2bu(float v) {
  unsigned u = __float_as_uint(v);
  u += 0x7fffu + ((u >> 16) & 1u);  // RNE
  return (unsigned short)(u >> 16);
}
// fp8 e4m3 (OCP on gfx950) HW conversions
__device__ __forceinline__ unsigned char f2fp8(float v) {
  return (unsigned char)(__builtin_amdgcn_cvt_pk_fp8_f32(v, v, 0, false) & 0xFF);
}
__device__ __forceinline__ void fp8x4_dec(unsigned v, float& a, float& b, float& c, float& d) {
  f32x2_t lo = __builtin_amdgcn_cvt_pk_f32_fp8(v, false);
  f32x2_t hi = __builtin_amdgcn_cvt_pk_f32_fp8(v, true);
  a = lo.x; b = lo.y; c = hi.x; d = hi.y;
}

// ==== fused prep: x cast (blks<castB) | W1/W2 transposed cast (next wB) | bucket hist ====
__global__ __launch_bounds__(256) void prep_kernel(
    const float4* __restrict__ x4, ushort4* __restrict__ xb4, int nx4,
    const float* __restrict__ W1, unsigned short* __restrict__ w1t,  // [256][128]
    const float* __restrict__ W2, unsigned short* __restrict__ w2t,  // [64][256]
    const int* __restrict__ ei, int* __restrict__ bhist, int E0, int Etot, int NBUCK,
    int castBlocks, int wBlocks, int histBlocks) {
  __shared__ int hsm[256];
  int t = threadIdx.x;
  if (blockIdx.x < (unsigned)castBlocks) {
    for (int i = blockIdx.x * 256 + t; i < nx4; i += castBlocks * 256) {
      float4 v = x4[i];
      xb4[i] = make_ushort4(f2bu(v.x), f2bu(v.y), f2bu(v.z), f2bu(v.w));
    }
  } else if (blockIdx.x < (unsigned)(castBlocks + wBlocks)) {
    int bid = blockIdx.x - castBlocks;
    const int tot1 = 128 * 256, tot2 = 256 * 64;
    for (int i = bid * 256 + t; i < tot1 + tot2; i += wBlocks * 256) {
      if (i < tot1) { int k = i >> 8, n = i & 255; w1t[n * 128 + k] = f2bu(W1[i]); }
      else { int j = i - tot1; int k = j >> 6, n = j & 63; w2t[n * 256 + k] = f2bu(W2[j]); }
    }
  } else {
    int bid = blockIdx.x - castBlocks - wBlocks;
    hsm[t] = 0;
    __syncthreads();
    for (int e = bid * 256 + t; e < Etot; e += histBlocks * 256) {
      int dst = (e < E0) ? ei[E0 + e] : (e - E0);
      atomicAdd(&hsm[dst >> 8], 1);
    }
    __syncthreads();
    if (t < NBUCK && hsm[t]) atomicAdd(&bhist[t], hsm[t]);
  }
}

// ================= bucket scan =================
__global__ __launch_bounds__(256) void bucket_scan_kernel(const int* __restrict__ bhist,
    int* __restrict__ bucketOff, int* __restrict__ cursor, int* __restrict__ rowptrN,
    int NBUCK, int Etot) {
  __shared__ int s[256];
  int t = threadIdx.x;
  int v = (t < NBUCK) ? bhist[t] : 0;
  s[t] = v;
  __syncthreads();
  for (int off = 1; off < 256; off <<= 1) {
    int u = (t >= off) ? s[t - off] : 0;
    __syncthreads();
    s[t] += u;
    __syncthreads();
  }
  int excl = s[t] - v;
  if (t < NBUCK) { bucketOff[t] = excl; cursor[t] = excl; }
  if (t == 0) { bucketOff[NBUCK] = Etot; *rowptrN = Etot; }
}

// ===== GEMM tile (bf16 MFMA, fp8 out) + alpha epilogue; B PRE-TRANSPOSED [Ncol][K] =====
// Both A and B staged with the same conflict-free pattern (lane copies 8 contiguous
// k-shorts of one row) — no in-kernel transpose, no bank conflicts.
__device__ void gemm_tile(const unsigned short* __restrict__ A,
    const unsigned short* __restrict__ BT, unsigned char* __restrict__ C8,
    const float* __restrict__ att_s, const float* __restrict__ att_d,
    float* __restrict__ as_, float* __restrict__ ad_,
    int M, int K, int Ncol, int H, int bx, int by, char* smem) {
  unsigned short (*Al)[40] = (unsigned short (*)[40])smem;           // 5120 B
  unsigned short (*Bt)[40] = (unsigned short (*)[40])(smem + 5120);  // 5120 B
  float* sal = (float*)(smem + 10240);  // [2][64]
  float* sad = (float*)(smem + 10752);  // [2][64]
  const int tid = threadIdx.x;
  const int row0 = by * 64, col0 = bx * 64;
  const int lane = tid & 63, wave = tid >> 6;
  const int wm = wave >> 1, wn = wave & 1;
  const int l15 = lane & 15, q = lane >> 4;

  f32x4 acc[2][2] = {};

  const int rr = tid >> 2, rc = (tid & 3) * 8;  // row 0..63, k-offset {0,8,16,24}

  for (int k0 = 0; k0 < K; k0 += 32) {
    // stage A
    ushort4 av0 = make_ushort4(0, 0, 0, 0), av1 = av0;
    if (row0 + rr < M) {
      const ushort4* ap = (const ushort4*)(A + (size_t)(row0 + rr) * K + k0 + rc);
      av0 = ap[0]; av1 = ap[1];
    }
    *(ushort4*)&Al[rr][rc] = av0;
    *(ushort4*)&Al[rr][rc + 4] = av1;
    // stage B (already [n][k])
    {
      const ushort4* bp = (const ushort4*)(BT + (size_t)(col0 + rr) * K + k0 + rc);
      *(ushort4*)&Bt[rr][rc] = bp[0];
      *(ushort4*)&Bt[rr][rc + 4] = bp[1];
    }
    __syncthreads();
    bf16x8 af[2], bf[2];
#pragma unroll
    for (int mi = 0; mi < 2; mi++)
      af[mi] = *(const bf16x8*)&Al[wm * 32 + mi * 16 + l15][q * 8];
#pragma unroll
    for (int ni = 0; ni < 2; ni++)
      bf[ni] = *(const bf16x8*)&Bt[wn * 32 + ni * 16 + l15][q * 8];
#pragma unroll
    for (int mi = 0; mi < 2; mi++)
#pragma unroll
      for (int ni = 0; ni < 2; ni++)
        acc[mi][ni] = __builtin_amdgcn_mfma_f32_16x16x32_bf16(af[mi], bf[ni], acc[mi][ni], 0, 0, 0);
    __syncthreads();
  }
  // fp8 store
#pragma unroll
  for (int mi = 0; mi < 2; mi++) {
#pragma unroll
    for (int r = 0; r < 4; r++) {
      int grow = row0 + wm * 32 + mi * 16 + q * 4 + r;
      if (grow < M) {
#pragma unroll
        for (int ni = 0; ni < 2; ni++) {
          int gcol = col0 + wn * 32 + ni * 16 + l15;
          C8[(size_t)grow * Ncol + gcol] = f2fp8(acc[mi][ni][r]);
        }
      }
    }
  }
  // alpha epilogue
  float atts0 = att_s[col0 + wn * 32 + l15];
  float atts1 = att_s[col0 + wn * 32 + 16 + l15];
  float attd0 = att_d[col0 + wn * 32 + l15];
  float attd1 = att_d[col0 + wn * 32 + 16 + l15];
#pragma unroll
  for (int mi = 0; mi < 2; mi++) {
#pragma unroll
    for (int r = 0; r < 4; r++) {
      float vs = acc[mi][0][r] * atts0 + acc[mi][1][r] * atts1;
      float vd = acc[mi][0][r] * attd0 + acc[mi][1][r] * attd1;
#pragma unroll
      for (int off = 1; off < 16; off <<= 1) {
        vs += __shfl_xor(vs, off);
        vd += __shfl_xor(vd, off);
      }
      if (l15 == 0) {
        int rl = wm * 32 + mi * 16 + q * 4 + r;
        sal[wn * 64 + rl] = vs;
        sad[wn * 64 + rl] = vd;
      }
    }
  }
  __syncthreads();
  if (tid < 64) {
    int grow = row0 + tid;
    if (grow < M) {
      as_[(size_t)grow * H + bx] = sal[tid] + sal[64 + tid];
      ad_[(size_t)grow * H + bx] = sad[tid] + sad[64 + tid];
    }
  }
}

__global__ __launch_bounds__(256) void gemm_alpha_kernel(const unsigned short* __restrict__ A,
    const unsigned short* __restrict__ BT, unsigned char* __restrict__ C8,
    const float* __restrict__ att_s, const float* __restrict__ att_d,
    float* __restrict__ as_, float* __restrict__ ad_, int M, int K, int Ncol, int H) {
  __shared__ __align__(16) char smem[11264];
  gemm_tile(A, BT, C8, att_s, att_d, as_, ad_, M, K, Ncol, H, blockIdx.x, blockIdx.y, smem);
}

// ================= fused: bucket scatter (blocks < NSC) || gemm1 =================
__global__ __launch_bounds__(256) void gemm1_scatter_kernel(
    const unsigned short* __restrict__ A, const unsigned short* __restrict__ BT,
    unsigned char* __restrict__ C8, const float* __restrict__ att_s,
    const float* __restrict__ att_d, float* __restrict__ as_, float* __restrict__ ad_,
    int M, int K, int Ncol, int H, int GX,
    const int* __restrict__ ei, int* __restrict__ cursor, int* __restrict__ pairs,
    int E0, int Etot, int NBUCK, int NSC) {
  __shared__ __align__(16) char smem[18432];
  if (blockIdx.x < (unsigned)NSC) {
    int2* stage = (int2*)smem;            // 16384 B
    int* h = (int*)(smem + 16384);        // 1024 B
    int* base = (int*)(smem + 17408);     // 1024 B
    int t = threadIdx.x;
    int e0 = blockIdx.x * CHUNK2;
    h[t] = 0;
    __syncthreads();
    int cnt = Etot - e0;
    if (cnt > CHUNK2) cnt = CHUNK2;
    for (int i = t; i < cnt; i += 256) {
      int e = e0 + i;
      int s, d;
      if (e < E0) { s = ei[e]; d = ei[E0 + e]; } else { s = d = e - E0; }
      stage[i] = make_int2((s << 8) | (d & 255), d >> 8);
      atomicAdd(&h[d >> 8], 1);
    }
    __syncthreads();
    if (t < NBUCK && h[t]) base[t] = atomicAdd(&cursor[t], h[t]);
    __syncthreads();
    for (int i = t; i < cnt; i += 256) {
      int2 p = stage[i];
      int pos = atomicAdd(&base[p.y], 1);
      pairs[pos] = p.x;
    }
  } else {
    int flat = blockIdx.x - NSC;
    gemm_tile(A, BT, C8, att_s, att_d, as_, ad_, M, K, Ncol, H, flat % GX, flat / GX, smem);
  }
}

// ================= per-bucket fine CSR =================
__global__ __launch_bounds__(256) void csr_build_kernel(const int* __restrict__ pairs,
    const int* __restrict__ bucketOff, int* __restrict__ rowptr, int* __restrict__ csr_src,
    int N) {
  int b = blockIdx.x, t = threadIdx.x;
  int base = bucketOff[b], cnt = bucketOff[b + 1] - base;
  int n0 = b << 8;
  __shared__ int h[256];
  __shared__ int s[256];
  __shared__ int ex[256];
  h[t] = 0;
  __syncthreads();
  for (int i = t; i < cnt; i += 256) atomicAdd(&h[pairs[base + i] & 255], 1);
  __syncthreads();
  int v = h[t];
  s[t] = v;
  __syncthreads();
  for (int off = 1; off < 256; off <<= 1) {
    int u = (t >= off) ? s[t - off] : 0;
    __syncthreads();
    s[t] += u;
    __syncthreads();
  }
  ex[t] = s[t] - v;
  if (n0 + t < N) rowptr[n0 + t] = base + ex[t];
  __syncthreads();
  for (int i = t; i < cnt; i += 256) {
    int p = pairs[base + i];
    int pos = atomicAdd(&ex[p & 255], 1);
    csr_src[base + pos] = ((unsigned)p) >> 8;
  }
}

// ================= layer-1 aggregate: quarter-wave per node, 16 ch/lane =================
__global__ __launch_bounds__(256) void aggr1_kernel(const int* __restrict__ rowptr,
    const int* __restrict__ csr_src, const float* __restrict__ as_,
    const float* __restrict__ ad_, const uint4* __restrict__ h1f8,  // [N][16] uint4
    const float* __restrict__ b1, unsigned short* __restrict__ out1, int Nn) {
  int lane = threadIdx.x & 63, wv = threadIdx.x >> 6;
  int q = lane >> 4, l15 = lane & 15;
  int n = (blockIdx.x * 4 + wv) * 4 + q;
  if (n >= Nn) return;
  int row = rowptr[n], deg = rowptr[n + 1] - row;
  int hh = l15 >> 2;
  float adv = ad_[n * 4 + hh];
  const uint4* hb = h1f8 + l15;
  float acc[16] = {};
  float wsum = 0.f;
  int s = 0;
  for (; s + 2 <= deg; s += 2) {
    int i0 = csr_src[row + s], i1 = csr_src[row + s + 1];
    float a0v = as_[i0 * 4 + hh], a1v = as_[i1 * 4 + hh];
    uint4 x0 = hb[(size_t)i0 * 16];
    uint4 x1 = hb[(size_t)i1 * 16];
    float w0 = __expf(lrelu(a0v + adv));
    float w1 = __expf(lrelu(a1v + adv));
    wsum += w0 + w1;
    float c0, c1, c2, c3;
    fp8x4_dec(x0.x, c0, c1, c2, c3);
    acc[0] = fmaf(w0, c0, acc[0]); acc[1] = fmaf(w0, c1, acc[1]);
    acc[2] = fmaf(w0, c2, acc[2]); acc[3] = fmaf(w0, c3, acc[3]);
    fp8x4_dec(x0.y, c0, c1, c2, c3);
    acc[4] = fmaf(w0, c0, acc[4]); acc[5] = fmaf(w0, c1, acc[5]);
    acc[6] = fmaf(w0, c2, acc[6]); acc[7] = fmaf(w0, c3, acc[7]);
    fp8x4_dec(x0.z, c0, c1, c2, c3);
    acc[8] = fmaf(w0, c0, acc[8]); acc[9] = fmaf(w0, c1, acc[9]);
    acc[10] = fmaf(w0, c2, acc[10]); acc[11] = fmaf(w0, c3, acc[11]);
    fp8x4_dec(x0.w, c0, c1, c2, c3);
    acc[12] = fmaf(w0, c0, acc[12]); acc[13] = fmaf(w0, c1, acc[13]);
    acc[14] = fmaf(w0, c2, acc[14]); acc[15] = fmaf(w0, c3, acc[15]);
    fp8x4_dec(x1.x, c0, c1, c2, c3);
    acc[0] = fmaf(w1, c0, acc[0]); acc[1] = fmaf(w1, c1, acc[1]);
    acc[2] = fmaf(w1, c2, acc[2]); acc[3] = fmaf(w1, c3, acc[3]);
    fp8x4_dec(x1.y, c0, c1, c2, c3);
    acc[4] = fmaf(w1, c0, acc[4]); acc[5] = fmaf(w1, c1, acc[5]);
    acc[6] = fmaf(w1, c2, acc[6]); acc[7] = fmaf(w1, c3, acc[7]);
    fp8x4_dec(x1.z, c0, c1, c2, c3);
    acc[8] = fmaf(w1, c0, acc[8]); acc[9] = fmaf(w1, c1, acc[9]);
    acc[10] = fmaf(w1, c2, acc[10]); acc[11] = fmaf(w1, c3, acc[11]);
    fp8x4_dec(x1.w, c0, c1, c2, c3);
    acc[12] = fmaf(w1, c0, acc[12]); acc[13] = fmaf(w1, c1, acc[13]);
    acc[14] = fmaf(w1, c2, acc[14]); acc[15] = fmaf(w1, c3, acc[15]);
  }
  if (s < deg) {
    int i0 = csr_src[row + s];
    float w0 = __expf(lrelu(as_[i0 * 4 + hh] + adv));
    wsum += w0;
    uint4 x0 = hb[(size_t)i0 * 16];
    float c0, c1, c2, c3;
    fp8x4_dec(x0.x, c0, c1, c2, c3);
    acc[0] = fmaf(w0, c0, acc[0]); acc[1] = fmaf(w0, c1, acc[1]);
    acc[2] = fmaf(w0, c2, acc[2]); acc[3] = fmaf(w0, c3, acc[3]);
    fp8x4_dec(x0.y, c0, c1, c2, c3);
    acc[4] = fmaf(w0, c0, acc[4]); acc[5] = fmaf(w0, c1, acc[5]);
    acc[6] = fmaf(w0, c2, acc[6]); acc[7] = fmaf(w0, c3, acc[7]);
    fp8x4_dec(x0.z, c0, c1, c2, c3);
    acc[8] = fmaf(w0, c0, acc[8]); acc[9] = fmaf(w0, c1, acc[9]);
    acc[10] = fmaf(w0, c2, acc[10]); acc[11] = fmaf(w0, c3, acc[11]);
    fp8x4_dec(x0.w, c0, c1, c2, c3);
    acc[12] = fmaf(w0, c0, acc[12]); acc[13] = fmaf(w0, c1, acc[13]);
    acc[14] = fmaf(w0, c2, acc[14]); acc[15] = fmaf(w0, c3, acc[15]);
  }
  float vinv = 1.f / wsum;
  int c0i = l15 * 16;
  unsigned short ob[16];
#pragma unroll
  for (int k = 0; k < 4; k++) {
    float4 bb = *(const float4*)(b1 + c0i + k * 4);
    float r0 = fmaf(acc[k * 4 + 0], vinv, bb.x);
    float r1 = fmaf(acc[k * 4 + 1], vinv, bb.y);
    float r2 = fmaf(acc[k * 4 + 2], vinv, bb.z);
    float r3 = fmaf(acc[k * 4 + 3], vinv, bb.w);
    ob[k * 4 + 0] = f2bu(r0 > 0.f ? r0 : 0.f);
    ob[k * 4 + 1] = f2bu(r1 > 0.f ? r1 : 0.f);
    ob[k * 4 + 2] = f2bu(r2 > 0.f ? r2 : 0.f);
    ob[k * 4 + 3] = f2bu(r3 > 0.f ? r3 : 0.f);
  }
  *(ushort4*)(out1 + (size_t)n * 256 + c0i) = *(ushort4*)&ob[0];
  *(ushort4*)(out1 + (size_t)n * 256 + c0i + 4) = *(ushort4*)&ob[4];
  *(ushort4*)(out1 + (size_t)n * 256 + c0i + 8) = *(ushort4*)&ob[8];
  *(ushort4*)(out1 + (size_t)n * 256 + c0i + 12) = *(ushort4*)&ob[12];
}

// ================= layer-2 aggregate + relu + pool (grouped atomics, unroll 8) =================
__global__ __launch_bounds__(256) void aggr2_pool_kernel(const int* __restrict__ rowptr,
    const int* __restrict__ csr_src, const float* __restrict__ as_,
    const float* __restrict__ ad_, const unsigned* __restrict__ h2f8,
    const float* __restrict__ b2, float* __restrict__ pooled_grp, int Nn) {
  int lane = threadIdx.x & 63, wv = threadIdx.x >> 6;
  int q = lane >> 4, l15 = lane & 15;
  int c0 = l15 * 4;
  const unsigned* hb = h2f8 + l15;
  float p0 = 0.f, p1 = 0.f, p2 = 0.f, p3 = 0.f;
  int stream = (blockIdx.x * 4 + wv) * 4 + q;
  int nstreams = gridDim.x * 16;
  for (int n = stream; n < Nn; n += nstreams) {
    int row = rowptr[n], deg = rowptr[n + 1] - row;
    float adv = ad_[n];
    float a0 = 0.f, a1 = 0.f, a2 = 0.f, a3 = 0.f, wsum = 0.f;
    int s = 0;
    for (; s + 8 <= deg; s += 8) {
      int idx[8];
      float al[8];
      unsigned xv[8];
#pragma unroll
      for (int j = 0; j < 8; j++) idx[j] = csr_src[row + s + j];
#pragma unroll
      for (int j = 0; j < 8; j++) al[j] = as_[idx[j]];
#pragma unroll
      for (int j = 0; j < 8; j++) xv[j] = hb[(size_t)idx[j] * 16];
#pragma unroll
      for (int j = 0; j < 8; j++) {
        float w = __expf(lrelu(al[j] + adv));
        wsum += w;
        float c0f, c1f, c2f, c3f;
        fp8x4_dec(xv[j], c0f, c1f, c2f, c3f);
        a0 = fmaf(w, c0f, a0); a1 = fmaf(w, c1f, a1);
        a2 = fmaf(w, c2f, a2); a3 = fmaf(w, c3f, a3);
      }
    }
    if (s + 4 <= deg) {
      int idx[4];
      float al[4];
      unsigned xv[4];
#pragma unroll
      for (int j = 0; j < 4; j++) idx[j] = csr_src[row + s + j];
#pragma unroll
      for (int j = 0; j < 4; j++) al[j] = as_[idx[j]];
#pragma unroll
      for (int j = 0; j < 4; j++) xv[j] = hb[(size_t)idx[j] * 16];
#pragma unroll
      for (int j = 0; j < 4; j++) {
        float w = __expf(lrelu(al[j] + adv));
        wsum += w;
        float c0f, c1f, c2f, c3f;
        fp8x4_dec(xv[j], c0f, c1f, c2f, c3f);
        a0 = fmaf(w, c0f, a0); a1 = fmaf(w, c1f, a1);
        a2 = fmaf(w, c2f, a2); a3 = fmaf(w, c3f, a3);
      }
      s += 4;
    }
    for (; s < deg; s++) {
      int i0 = csr_src[row + s];
      float w = __expf(lrelu(as_[i0] + adv));
      wsum += w;
      float c0f, c1f, c2f, c3f;
      fp8x4_dec(hb[(size_t)i0 * 16], c0f, c1f, c2f, c3f);
      a0 = fmaf(w, c0f, a0); a1 = fmaf(w, c1f, a1);
      a2 = fmaf(w, c2f, a2); a3 = fmaf(w, c3f, a3);
    }
    float vinv = 1.f / wsum;
    float4 bb = *(const float4*)(b2 + c0);
    float r0 = fmaf(a0, vinv, bb.x), r1 = fmaf(a1, vinv, bb.y);
    float r2 = fmaf(a2, vinv, bb.z), r3 = fmaf(a3, vinv, bb.w);
    p0 += r0 > 0.f ? r0 : 0.f; p1 += r1 > 0.f ? r1 : 0.f;
    p2 += r2 > 0.f ? r2 : 0.f; p3 += r3 > 0.f ? r3 : 0.f;
  }
  __shared__ float4 sred[4][4][16];
  sred[wv][q][l15] = make_float4(p0, p1, p2, p3);
  __syncthreads();
  if (threadIdx.x < 64) {
    int slot = threadIdx.x >> 2, comp = threadIdx.x & 3;
    float acc = 0.f;
#pragma unroll
    for (int i = 0; i < 4; i++)
#pragma unroll
      for (int j = 0; j < 4; j++) {
        float4 v = sred[i][j][slot];
        acc += comp == 0 ? v.x : (comp == 1 ? v.y : (comp == 2 ? v.z : v.w));
      }
    atomicAdd(&pooled_grp[(blockIdx.x & (PGROUPS - 1)) * 64 + slot * 4 + comp], acc);
  }
}

// ================= pooled_grp[32][64] -> fc + log_softmax (one block) =================
__global__ __launch_bounds__(64) void pool_head_kernel(const float* __restrict__ pooled_grp,
    const float* __restrict__ fc_w, const float* __restrict__ fc_b,
    float* __restrict__ out, float invN) {
  int t = threadIdx.x;
  __shared__ float pl[64];
  __shared__ float lg[40];
  __shared__ float lse;
  float acc = 0.f;
#pragma unroll
  for (int g = 0; g < PGROUPS; g++) acc += pooled_grp[g * 64 + t];
  pl[t] = acc * invN;
  __syncthreads();
  if (t < 40) {
    float sm = fc_b[t];
    for (int c = 0; c < 64; c++) sm = fmaf(pl[c], fc_w[c * 40 + t], sm);
    lg[t] = sm;
  }
  __syncthreads();
  if (t == 0) {
    float m = -1e30f;
    for (int j = 0; j < 40; j++) m = fmaxf(m, lg[j]);
    float su = 0.f;
    for (int j = 0; j < 40; j++) su += expf(lg[j] - m);
    lse = m + logf(su);
  }
  __syncthreads();
  if (t < 40) out[t] = lg[t] - lse;
}

extern "C" void kernel_launch(void* const* d_in, const int* in_sizes, int n_in,
                              void* d_out, int out_size, void* d_ws, size_t ws_size,
                              hipStream_t stream) {
  const float* x        = (const float*)d_in[0];
  const int*   ei       = (const int*)d_in[1];
  const float* W1       = (const float*)d_in[2];
  const float* att_src1 = (const float*)d_in[3];
  const float* att_dst1 = (const float*)d_in[4];
  const float* b1       = (const float*)d_in[5];
  const float* W2       = (const float*)d_in[6];
  const float* att_src2 = (const float*)d_in[7];
  const float* att_dst2 = (const float*)d_in[8];
  const float* b2       = (const float*)d_in[9];
  const float* fc_w     = (const float*)d_in[10];
  const float* fc_b     = (const float*)d_in[11];
  float* out = (float*)d_out;

  const int N    = in_sizes[0] / 128;  // 50000
  const int E0   = in_sizes[1] / 2;    // 800000
  const int Etot = E0 + N;
  const int NBUCK = (N + 255) >> 8;               // 196
  const int NSC  = (Etot + CHUNK2 - 1) / CHUNK2;  // 416
  const int GBY  = (N + 63) / 64;                 // 782
  const int AGG2_BLOCKS = 2048;

  char* wsb = (char*)d_ws;
  size_t o = 0;
  auto alloc = [&](size_t bytes) { char* p = wsb + o; o += (bytes + 15) & ~(size_t)15; return p; };
  unsigned short* xb   = (unsigned short*)alloc((size_t)N * 128 * 2);
  unsigned short* w1t  = (unsigned short*)alloc(256 * 128 * 2);       // transposed [256][128]
  unsigned short* w2t  = (unsigned short*)alloc(64 * 256 * 2);        // transposed [64][256]
  unsigned char*  h1f8 = (unsigned char*)alloc((size_t)N * 256);      // fp8; reused as h2 fp8
  unsigned short* out1 = (unsigned short*)alloc((size_t)N * 256 * 2); // bf16
  float* as1  = (float*)alloc((size_t)N * 4 * 4);
  float* ad1  = (float*)alloc((size_t)N * 4 * 4);
  float* as2  = (float*)alloc((size_t)N * 4);
  float* ad2  = (float*)alloc((size_t)N * 4);
  int* rowptr = (int*)alloc((size_t)(N + 1) * 4);
  int* bhist  = (int*)alloc(256 * 4);
  int* bucketOff = (int*)alloc(257 * 4);
  int* cursor = (int*)alloc(256 * 4);
  int* pairs  = (int*)alloc((size_t)Etot * 4);
  int* csr_src = (int*)alloc((size_t)Etot * 4);
  float* pooled_grp = (float*)alloc((size_t)PGROUPS * 64 * 4);

  dim3 blk(256);

  // ---- prep: x cast || W transpose-cast || bucket hist ----
  hipMemsetAsync(bhist, 0, 256 * sizeof(int), stream);
  hipMemsetAsync(pooled_grp, 0, (size_t)PGROUPS * 64 * sizeof(float), stream);
  prep_kernel<<<512 + 16 + 256, blk, 0, stream>>>(
      (const float4*)x, (ushort4*)xb, N * 128 / 4,
      W1, w1t, W2, w2t,
      ei, bhist, E0, Etot, NBUCK, 512, 16, 256);
  bucket_scan_kernel<<<1, blk, 0, stream>>>(bhist, bucketOff, cursor, rowptr + N, NBUCK, Etot);

  // ---- gemm1 (+alpha1 epilogue) || bucket scatter ----
  gemm1_scatter_kernel<<<NSC + 4 * GBY, blk, 0, stream>>>(
      xb, w1t, h1f8, att_src1, att_dst1, as1, ad1, N, 128, 256, 4, 4,
      ei, cursor, pairs, E0, Etot, NBUCK, NSC);
  csr_build_kernel<<<NBUCK, blk, 0, stream>>>(pairs, bucketOff, rowptr, csr_src, N);

  // ---- layer-1 aggregate (quarter-wave, 16 nodes/block) ----
  aggr1_kernel<<<(N + 15) / 16, blk, 0, stream>>>(rowptr, csr_src, as1, ad1,
                                                  (const uint4*)h1f8, b1, out1, N);

  // ---- layer 2: gemm2 (+alpha2 epilogue), aggregate + grouped pool atomics ----
  gemm_alpha_kernel<<<dim3(1, GBY), blk, 0, stream>>>(out1, w2t, h1f8, att_src2, att_dst2,
                                                      as2, ad2, N, 256, 64, 1);
  aggr2_pool_kernel<<<AGG2_BLOCKS, blk, 0, stream>>>(rowptr, csr_src, as2, ad2,
                                                     (const unsigned*)h1f8, b2, pooled_grp, N);

  // ---- epilogue ----
  pool_head_kernel<<<1, 64, 0, stream>>>(pooled_grp, fc_w, fc_b, out, 1.0f / (float)N);
}